// Round 9
// baseline (116.237 us; speedup 1.0000x reference)
//
#include <hip/hip_runtime.h>

// ContrastiveLoss on MI355X — r1-proven gram body (16KB single-buffer,
// 2 barriers/K-step, VGPR~76, NO min-waves clause) + compact 528-tile
// upper-triangle lists + XOR chunk swizzle (both-sides, rule #21).
// Plus ONE diagnostic dispatch: same kernel, reps=4, epilogue->dump,
// to expose steady-state counters in rocprof top-5 (dropped next round).

#define KGRP 8
#define FD   512
#define N1T  2048
#define NT   4096
#define TEMPW 0.02f

typedef __attribute__((ext_vector_type(8))) short short8;
typedef __attribute__((ext_vector_type(4))) float f32x4;
typedef unsigned short ushort_t;

// ---- helpers ---------------------------------------------------------------

__device__ __forceinline__ unsigned enc_ord(float f) {
  unsigned u = __float_as_uint(f);
  return (u & 0x80000000u) ? ~u : (u | 0x80000000u);
}
__device__ __forceinline__ float dec_ord(unsigned u) {
  unsigned b = (u & 0x80000000u) ? (u & 0x7fffffffu) : ~u;
  return __uint_as_float(b);
}

__device__ __forceinline__ ushort_t f2bf(float f) {
  unsigned u = __float_as_uint(f);
  u = (u + 0x7fffu + ((u >> 16) & 1u)) >> 16;
  return (ushort_t)u;
}

__device__ __forceinline__ void gld16(const void* g, void* l) {
  __builtin_amdgcn_global_load_lds(
      (const __attribute__((address_space(1))) unsigned*)g,
      (__attribute__((address_space(3))) unsigned*)l, 16, 0, 0);
}

// cnts layout: [0]=nn [1]=np [2]=pos done counter

// ---- prep: bf16 convert + zero accumulators + class table + tile lists -----
__global__ __launch_bounds__(256) void prep_k(
    const float* __restrict__ f1, const float* __restrict__ f2,
    ushort_t* __restrict__ bf,
    float* __restrict__ neg_sum, unsigned* __restrict__ neg_max,
    float* __restrict__ sumS, float* __restrict__ corr,
    int* __restrict__ cnts, int* __restrict__ neg_list,
    int* __restrict__ pos_list, const int* __restrict__ ov)
{
  const int b = blockIdx.x, t = threadIdx.x;

  {
    int i = b * 256 + t;
    size_t base = (size_t)i * 8;
    const size_t half = (size_t)N1T * FD;
    const float* sp = (base < half) ? (f1 + base) : (f2 + (base - half));
    float4 u0 = ((const float4*)sp)[0];
    float4 u1 = ((const float4*)sp)[1];
    short8 o;
    o[0] = (short)f2bf(u0.x); o[1] = (short)f2bf(u0.y);
    o[2] = (short)f2bf(u0.z); o[3] = (short)f2bf(u0.w);
    o[4] = (short)f2bf(u1.x); o[5] = (short)f2bf(u1.y);
    o[6] = (short)f2bf(u1.z); o[7] = (short)f2bf(u1.w);
    *(short8*)(bf + base) = o;
  }

  if (b >= 1 && b <= 16) {
    int i = (b - 1) * 256 + t;
    neg_sum[i] = 0.f;
    neg_max[i] = 0u;                    // 0u < enc_ord(any float)
  }

  if (b == 0) {
    __shared__ int c[16];
    if (t == 0) {
      sumS[0] = 0.f; corr[0] = 0.f;
      cnts[0] = 0; cnts[1] = 0; cnts[2] = 0;
      int excl = 0;
      for (int g = 0; g < KGRP; g++) c[g] = g;
      for (int g = 0; g < KGRP; g++) {
        if (ov[g]) c[KGRP + g] = g;
        else       { c[KGRP + g] = KGRP + excl; excl++; }
      }
    }
    __syncthreads();
    for (int p = t; p < 1024; p += 256) {
      int bi = p >> 5, bj = p & 31;
      if (bj < bi) continue;
      if (c[bi >> 1] == c[bj >> 1]) {
        int k = atomicAdd(&cnts[1], 1); pos_list[k] = (bi << 5) | bj;
      } else {
        int k = atomicAdd(&cnts[0], 1); neg_list[k] = (bi << 5) | bj;
      }
    }
  }
}

// ---- gram pass over all 528 upper-triangle tiles ---------------------------
// 16 KB LDS single buffer, 2 barriers/K-step. reps>1 + dump => diagnostic
// mode: K-loop repeated, epilogue replaced by per-thread acc dump (no
// atomics), used only to surface steady-state counters in rocprof.
__global__ __launch_bounds__(256) void gram_k(
    const ushort_t* __restrict__ bf, const int* __restrict__ cnts,
    const int* __restrict__ neg_list, const int* __restrict__ pos_list,
    float* __restrict__ neg_sum, unsigned* __restrict__ neg_max,
    float* __restrict__ pos_dots, int reps, float* __restrict__ dump)
{
  __shared__ char lds[16384];           // A 8KB | B 8KB

  const int nn = cnts[0];
  const int b  = blockIdx.x;
  const bool isneg = (b < nn);
  const int pr = isneg ? neg_list[b] : pos_list[b - nn];
  const int bi = pr >> 5, bj = pr & 31;
  const int brow = bi << 7, bcol = bj << 7;

  const int t    = threadIdx.x;
  const int lane = t & 63, wave = t >> 6;
  const int wrow = (wave >> 1) << 6, wcol = (wave & 1) << 6;
  const int fr   = lane & 15, fh = lane >> 4;

  // staging source: row r_in = t>>2, 16B chunk (t&3) XOR-swizzled by row
  const int r_in = t >> 2;
  const int csw  = (((t & 3) ^ ((t >> 3) & 3)) << 3);   // elems
  const ushort_t* gA = bf + (size_t)(brow + r_in) * FD + csw;
  const ushort_t* gB = bf + (size_t)(bcol + r_in) * FD + csw;
  const int ldsw = wave << 10;          // wave-uniform LDS byte offset

  // fragment read byte offsets (same XOR on the read side)
  const int fx = ((fh ^ ((fr >> 1) & 3)) << 4);
  int offA[4], offB[4];
#pragma unroll
  for (int m = 0; m < 4; m++) offA[m] = ((wrow + (m << 4) + fr) << 6) + fx;
#pragma unroll
  for (int n = 0; n < 4; n++) offB[n] = 8192 + ((wcol + (n << 4) + fr) << 6) + fx;

  f32x4 acc[4][4];
#pragma unroll
  for (int m = 0; m < 4; m++)
#pragma unroll
    for (int n = 0; n < 4; n++)
      acc[m][n] = (f32x4){0.f, 0.f, 0.f, 0.f};

  for (int rep = 0; rep < reps; rep++) {
    for (int s = 0; s < 16; s++) {
      {
        char* dst = lds + ldsw;
        const ushort_t* a = gA + (s << 5);
        const ushort_t* p = gB + (s << 5);
        gld16(a,                   dst);
        gld16(a + (size_t)64 * FD, dst + 4096);
        gld16(p,                   dst + 8192);
        gld16(p + (size_t)64 * FD, dst + 12288);
      }
      __syncthreads();                  // drains vmcnt + barrier

      short8 a[4], bb[4];
#pragma unroll
      for (int m = 0; m < 4; m++) a[m]  = *(const short8*)(lds + offA[m]);
#pragma unroll
      for (int n = 0; n < 4; n++) bb[n] = *(const short8*)(lds + offB[n]);

#pragma unroll
      for (int m = 0; m < 4; m++)
#pragma unroll
        for (int n = 0; n < 4; n++)
          acc[m][n] = __builtin_amdgcn_mfma_f32_16x16x32_bf16(a[m], bb[n], acc[m][n], 0, 0, 0);
      __syncthreads();                  // WAR: reads done before next stage
    }
  }

  if (dump) {                           // diagnostic mode: keep acc live, exit
    float ssum = 0.f;
#pragma unroll
    for (int m = 0; m < 4; m++)
#pragma unroll
      for (int n = 0; n < 4; n++)
#pragma unroll
        for (int j = 0; j < 4; j++) ssum += acc[m][n][j];
    dump[(size_t)b * 256 + t] = ssum;
    return;
  }

  const int rbase = brow + wrow + (fh << 2);
  const int cbase = bcol + wcol + fr;

  if (isneg) {
    // single-exp epilogue: row sums/maxes + column sums/maxes in one sweep
    float colS[4] = {0.f, 0.f, 0.f, 0.f};
    float colM[4] = {-3.0e38f, -3.0e38f, -3.0e38f, -3.0e38f};
#pragma unroll
    for (int m = 0; m < 4; m++) {
#pragma unroll
      for (int j = 0; j < 4; j++) {
        float s = 0.f, mx = -3.0e38f;
#pragma unroll
        for (int n = 0; n < 4; n++) {
          float d = acc[m][n][j];
          float e = __expf(d * TEMPW);
          s += e; mx = fmaxf(mx, d);
          colS[n] += e; colM[n] = fmaxf(colM[n], d);
        }
#pragma unroll
        for (int o = 1; o < 16; o <<= 1) {
          s  += __shfl_xor(s, o, 64);
          mx  = fmaxf(mx, __shfl_xor(mx, o, 64));
        }
        if (fr == 0) {
          int r = rbase + (m << 4) + j;
          atomicAdd(&neg_sum[r], s);
          atomicMax(&neg_max[r], enc_ord(mx));
        }
      }
    }
#pragma unroll
    for (int n = 0; n < 4; n++) {
      float s = colS[n], mx = colM[n];
      s += __shfl_xor(s, 16, 64); mx = fmaxf(mx, __shfl_xor(mx, 16, 64));
      s += __shfl_xor(s, 32, 64); mx = fmaxf(mx, __shfl_xor(mx, 32, 64));
      if (fh == 0) {
        int c = cbase + (n << 4);
        atomicAdd(&neg_sum[c], s);
        atomicMax(&neg_max[c], enc_ord(mx));
      }
    }
  } else {
    // pos tile: dump dots to scratch (compared after neg_max is final)
    float* basep = pos_dots + (size_t)(b - nn) * 16384;
#pragma unroll
    for (int m = 0; m < 4; m++)
#pragma unroll
      for (int n = 0; n < 4; n++)
        *(f32x4*)(basep + (((m << 2) + n) << 10) + (t << 2)) = acc[m][n];
  }
}

// ---- fused pos-compare + finalize (last pos block runs the finalize) -------
__global__ __launch_bounds__(256) void pos_fin_k(
    const float* __restrict__ pos_dots, const int* __restrict__ cnts,
    const int* __restrict__ pos_list, const unsigned* __restrict__ neg_max,
    const float* __restrict__ neg_sum, const int* __restrict__ ov,
    float* __restrict__ sumS, float* __restrict__ corr,
    int* __restrict__ done, float* __restrict__ out)
{
  const int np = cnts[1];
  const int p  = blockIdx.x;
  const int t  = threadIdx.x, lane = t & 63, wave = t >> 6;

  __shared__ float wsum[4];
  __shared__ int   wcnt[4];
  __shared__ int   amLast;

  if (p < np) {
    const int pr = pos_list[p];
    const int bi = pr >> 5, bj = pr & 31;
    const int wrow = (wave >> 1) << 6, wcol = (wave & 1) << 6;
    const int fr = lane & 15, fh = lane >> 4;
    const int rbase = (bi << 7) + wrow + (fh << 2);
    const int cbase = (bj << 7) + wcol + fr;
    const float cw = ((bi < 16) == (bj < 16)) ? 1.0f : 0.5f;
    const float* basep = pos_dots + (size_t)p * 16384;

    float ssum = 0.f;
    int cc = 0;
    if (bi == bj) {
#pragma unroll
      for (int m = 0; m < 4; m++)
#pragma unroll
        for (int n = 0; n < 4; n++) {
          f32x4 v = *(const f32x4*)(basep + (((m << 2) + n) << 10) + (t << 2));
          int c = cbase + (n << 4);
#pragma unroll
          for (int j = 0; j < 4; j++) {
            int r = rbase + (m << 4) + j;
            if (r != c) {
              float d = v[j];
              ssum += d;
              cc += (d > dec_ord(neg_max[r])) ? 1 : 0;
            }
          }
        }
    } else {
      float nmr[4][4], nmc[4];
#pragma unroll
      for (int m = 0; m < 4; m++)
#pragma unroll
        for (int j = 0; j < 4; j++) nmr[m][j] = dec_ord(neg_max[rbase + (m << 4) + j]);
#pragma unroll
      for (int n = 0; n < 4; n++) nmc[n] = dec_ord(neg_max[cbase + (n << 4)]);
#pragma unroll
      for (int m = 0; m < 4; m++)
#pragma unroll
        for (int n = 0; n < 4; n++) {
          f32x4 v = *(const f32x4*)(basep + (((m << 2) + n) << 10) + (t << 2));
#pragma unroll
          for (int j = 0; j < 4; j++) {
            float d = v[j];
            ssum += d;
            cc += ((d > nmr[m][j]) ? 1 : 0) + ((d > nmc[n]) ? 1 : 0);
          }
        }
      ssum *= 2.0f;   // both orientations
    }
    ssum *= cw;

#pragma unroll
    for (int o = 1; o < 64; o <<= 1) {
      ssum += __shfl_xor(ssum, o, 64);
      cc   += __shfl_xor(cc, o, 64);
    }
    if (lane == 0) { wsum[wave] = ssum; wcnt[wave] = cc; }
    __syncthreads();
    if (t == 0) {
      float S2 = 0.f; int C2 = 0;
      for (int w = 0; w < 4; w++) { S2 += wsum[w]; C2 += wcnt[w]; }
      atomicAdd(sumS, S2);
      atomicAdd(corr, (float)C2);
    }
  }

  // completion detection (block-uniform broadcast via shared)
  if (t == 0) {
    int my = -1;
    if (p < np) { __threadfence(); my = atomicAdd(done, 1); }
    amLast = (my == np - 1) ? 1 : 0;
  }
  __syncthreads();
  if (!amLast) return;
  __threadfence();

  // finalize: loss = (sum_r W_r*log(neg_sum_r) - TEMP*sumS) / total_pos
  float aa = 0.f;
  for (int r = t; r < NT; r += 256) {
    int g = r >> 8;                     // 256-row group, 0..15
    float W = ov[g & 7] ? 383.f : 255.f;
    aa += W * __logf(neg_sum[r]);
  }
#pragma unroll
  for (int o = 1; o < 64; o <<= 1) aa += __shfl_xor(aa, o, 64);
  if (lane == 0) wsum[wave] = aa;
  __syncthreads();
  if (t == 0) {
    float sw = wsum[0] + wsum[1] + wsum[2] + wsum[3];
    float S = atomicAdd(sumS, 0.f);     // coherent read past L1
    float C = atomicAdd(corr, 0.f);
    float tp = 0.f;
    for (int g = 0; g < 16; g++) tp += 256.f * (255.f + 256.f * (ov[g & 7] ? 1.f : 0.f));
    out[0] = C / tp;
    out[1] = (sw - TEMPW * S) / tp;
  }
}

// ---- launch ----------------------------------------------------------------

extern "C" void kernel_launch(void* const* d_in, const int* in_sizes, int n_in,
                              void* d_out, int out_size, void* d_ws, size_t ws_size,
                              hipStream_t stream)
{
  const float* f1 = (const float*)d_in[0];
  const float* f2 = (const float*)d_in[1];
  const int*   ov = (const int*)d_in[2];

  char* ws = (char*)d_ws;
  ushort_t* bf       = (ushort_t*)ws;                                    // 4 MB
  float*    neg_sum  = (float*)(ws + (size_t)(4 << 20));                 // 16 KB
  unsigned* neg_max  = (unsigned*)(ws + (size_t)(4 << 20) + (16 << 10)); // 16 KB
  float*    sumS     = (float*)(ws + (size_t)(4 << 20) + (32 << 10));
  float*    corr     = sumS + 1;
  int*      cnts     = (int*)(sumS + 2);                                 // 3 ints
  int*      done     = cnts + 2;                                         // alias cnts[2]
  int*      neg_list = (int*)(ws + (size_t)(4 << 20) + (36 << 10));      // <=496
  int*      pos_list = (int*)(ws + (size_t)(4 << 20) + (40 << 10));      // <=80
  float*    pos_dots = (float*)(ws + (size_t)(4 << 20) + (64 << 10));    // 5.25 MB
  float*    dumpbuf  = (float*)(ws + (size_t)(16 << 20));                // 540 KB diag
  float*    out      = (float*)d_out;

  hipLaunchKernelGGL(prep_k, dim3(1024), dim3(256), 0, stream,
                     f1, f2, bf, neg_sum, neg_max, sumS, corr, cnts,
                     neg_list, pos_list, ov);
  hipLaunchKernelGGL(gram_k, dim3(528), dim3(256), 0, stream,
                     bf, cnts, neg_list, pos_list, neg_sum, neg_max, pos_dots,
                     1, (float*)nullptr);
  hipLaunchKernelGGL(pos_fin_k, dim3(80), dim3(256), 0, stream,
                     pos_dots, cnts, pos_list, neg_max, neg_sum, ov,
                     sumS, corr, done, out);
  // diagnostic dispatch (dropped next round): same body, 4x K-loop, no
  // atomics, dump keeps acc live. Surfaces steady-state counters in top-5.
  hipLaunchKernelGGL(gram_k, dim3(528), dim3(256), 0, stream,
                     bf, cnts, neg_list, pos_list, neg_sum, neg_max, pos_dots,
                     4, dumpbuf);
}

// Round 10
// 55.427 us; speedup vs baseline: 2.0971x; 2.0971x over previous
//
#include <hip/hip_runtime.h>

// ContrastiveLoss on MI355X — symmetric Gram; BK=64 single-buffer gram body.
// r9 diagnostic: 2-barrier loop at BK=32 costs ~1100 cyc/step of which only
// ~155 is MFMA; the fixed stall is the vmcnt(0)+barrier drain. BK=64 halves
// the number of drains (8 steps instead of 16) at the same occupancy
// (32 KB LDS, VGPR~104 -> ~4 blocks/CU cap, grid 528 -> 2.06/CU anyway).
// T2-style swizzle at 128B row stride: LDS slot (row, chunk c) holds global
// chunk c ^ (row&7); staged via XOR on the GLOBAL source (linear LDS dest,
// rule #21), read at chunk ((ks*4+fh) ^ (fr&7)) -> 2-way = free (m136).
// Upper triangle only (528 class-uniform 128x128 tiles): neg tiles
// accumulate row+col exp-sums/maxes; pos tiles dump dots, compared +
// finalized in pos_fin_k.

#define KGRP 8
#define FD   512
#define N1T  2048
#define NT   4096
#define TEMPW 0.02f

typedef __attribute__((ext_vector_type(8))) short short8;
typedef __attribute__((ext_vector_type(4))) float f32x4;
typedef unsigned short ushort_t;

// ---- helpers ---------------------------------------------------------------

__device__ __forceinline__ unsigned enc_ord(float f) {
  unsigned u = __float_as_uint(f);
  return (u & 0x80000000u) ? ~u : (u | 0x80000000u);
}
__device__ __forceinline__ float dec_ord(unsigned u) {
  unsigned b = (u & 0x80000000u) ? (u & 0x7fffffffu) : ~u;
  return __uint_as_float(b);
}

__device__ __forceinline__ ushort_t f2bf(float f) {
  unsigned u = __float_as_uint(f);
  u = (u + 0x7fffu + ((u >> 16) & 1u)) >> 16;
  return (ushort_t)u;
}

__device__ __forceinline__ void gld16(const void* g, void* l) {
  __builtin_amdgcn_global_load_lds(
      (const __attribute__((address_space(1))) unsigned*)g,
      (__attribute__((address_space(3))) unsigned*)l, 16, 0, 0);
}

// cnts layout: [0]=nn [1]=np [2]=pos done counter

// ---- prep: bf16 convert + zero accumulators + class table + tile lists -----
__global__ __launch_bounds__(256) void prep_k(
    const float* __restrict__ f1, const float* __restrict__ f2,
    ushort_t* __restrict__ bf,
    float* __restrict__ neg_sum, unsigned* __restrict__ neg_max,
    float* __restrict__ sumS, float* __restrict__ corr,
    int* __restrict__ cnts, int* __restrict__ neg_list,
    int* __restrict__ pos_list, const int* __restrict__ ov)
{
  const int b = blockIdx.x, t = threadIdx.x;

  {
    int i = b * 256 + t;
    size_t base = (size_t)i * 8;
    const size_t half = (size_t)N1T * FD;
    const float* sp = (base < half) ? (f1 + base) : (f2 + (base - half));
    float4 u0 = ((const float4*)sp)[0];
    float4 u1 = ((const float4*)sp)[1];
    short8 o;
    o[0] = (short)f2bf(u0.x); o[1] = (short)f2bf(u0.y);
    o[2] = (short)f2bf(u0.z); o[3] = (short)f2bf(u0.w);
    o[4] = (short)f2bf(u1.x); o[5] = (short)f2bf(u1.y);
    o[6] = (short)f2bf(u1.z); o[7] = (short)f2bf(u1.w);
    *(short8*)(bf + base) = o;
  }

  if (b >= 1 && b <= 16) {
    int i = (b - 1) * 256 + t;
    neg_sum[i] = 0.f;
    neg_max[i] = 0u;                    // 0u < enc_ord(any float)
  }

  if (b == 0) {
    __shared__ int c[16];
    if (t == 0) {
      sumS[0] = 0.f; corr[0] = 0.f;
      cnts[0] = 0; cnts[1] = 0; cnts[2] = 0;
      int excl = 0;
      for (int g = 0; g < KGRP; g++) c[g] = g;
      for (int g = 0; g < KGRP; g++) {
        if (ov[g]) c[KGRP + g] = g;
        else       { c[KGRP + g] = KGRP + excl; excl++; }
      }
    }
    __syncthreads();
    for (int p = t; p < 1024; p += 256) {
      int bi = p >> 5, bj = p & 31;
      if (bj < bi) continue;
      if (c[bi >> 1] == c[bj >> 1]) {
        int k = atomicAdd(&cnts[1], 1); pos_list[k] = (bi << 5) | bj;
      } else {
        int k = atomicAdd(&cnts[0], 1); neg_list[k] = (bi << 5) | bj;
      }
    }
  }
}

// ---- gram pass over all 528 upper-triangle tiles, BK=64 --------------------
__global__ __launch_bounds__(256) void gram_k(
    const ushort_t* __restrict__ bf, const int* __restrict__ cnts,
    const int* __restrict__ neg_list, const int* __restrict__ pos_list,
    float* __restrict__ neg_sum, unsigned* __restrict__ neg_max,
    float* __restrict__ pos_dots)
{
  __shared__ char lds[32768];           // A[128][64] 16KB | B[128][64] 16KB

  const int nn = cnts[0];
  const int b  = blockIdx.x;
  const bool isneg = (b < nn);
  const int pr = isneg ? neg_list[b] : pos_list[b - nn];
  const int bi = pr >> 5, bj = pr & 31;
  const int brow = bi << 7, bcol = bj << 7;

  const int t    = threadIdx.x;
  const int lane = t & 63, wave = t >> 6;
  const int wrow = (wave >> 1) << 6, wcol = (wave & 1) << 6;
  const int fr   = lane & 15, fh = lane >> 4;

  // staging: instr j covers rows j*32 + wave*8 + (lane>>3), chunk (lane&7)
  // of a [128][64] bf16 tile (128B rows). Global chunk = slot ^ (row&7).
  const int row8 = lane >> 3;           // 0..7
  const int cswz = ((lane & 7) ^ row8) << 3;   // elems
  const ushort_t* gA = bf + (size_t)(brow + (wave << 3) + row8) * FD + cswz;
  const ushort_t* gB = bf + (size_t)(bcol + (wave << 3) + row8) * FD + cswz;
  char* const dstA = lds         + (wave << 10);   // + j*4096, lane*16 implicit
  char* const dstB = lds + 16384 + (wave << 10);

  // fragment read byte offsets: row*128 + (((ks*4+fh) ^ (fr&7)) * 16)
  int offA[2][4], offB[2][4];
#pragma unroll
  for (int ks = 0; ks < 2; ks++) {
    const int cx = (((ks << 2) | fh) ^ (fr & 7)) << 4;
#pragma unroll
    for (int m = 0; m < 4; m++) offA[ks][m] = ((wrow + (m << 4) + fr) << 7) + cx;
#pragma unroll
    for (int n = 0; n < 4; n++) offB[ks][n] = 16384 + ((wcol + (n << 4) + fr) << 7) + cx;
  }

  f32x4 acc[4][4];
#pragma unroll
  for (int m = 0; m < 4; m++)
#pragma unroll
    for (int n = 0; n < 4; n++)
      acc[m][n] = (f32x4){0.f, 0.f, 0.f, 0.f};

  for (int s = 0; s < 8; s++) {         // 8 K-steps of 64
    // stage A[128][64] + B[128][64] for K-slice s (8 gld16/thread)
#pragma unroll
    for (int j = 0; j < 4; j++) {
      gld16(gA + (size_t)j * 32 * FD + (s << 6), dstA + (j << 12));
      gld16(gB + (size_t)j * 32 * FD + (s << 6), dstB + (j << 12));
    }
    __syncthreads();                    // drains vmcnt+lgkm, then barrier

#pragma unroll
    for (int ks = 0; ks < 2; ks++) {
      short8 a[4], bb[4];
#pragma unroll
      for (int m = 0; m < 4; m++) a[m]  = *(const short8*)(lds + offA[ks][m]);
#pragma unroll
      for (int n = 0; n < 4; n++) bb[n] = *(const short8*)(lds + offB[ks][n]);
#pragma unroll
      for (int m = 0; m < 4; m++)
#pragma unroll
        for (int n = 0; n < 4; n++)
          acc[m][n] = __builtin_amdgcn_mfma_f32_16x16x32_bf16(a[m], bb[n], acc[m][n], 0, 0, 0);
    }
    __syncthreads();                    // WAR: reads done before next stage
  }

  const int rbase = brow + wrow + (fh << 2);
  const int cbase = bcol + wcol + fr;

  if (isneg) {
    // single-exp epilogue: row sums/maxes + column sums/maxes in one sweep
    float colS[4] = {0.f, 0.f, 0.f, 0.f};
    float colM[4] = {-3.0e38f, -3.0e38f, -3.0e38f, -3.0e38f};
#pragma unroll
    for (int m = 0; m < 4; m++) {
#pragma unroll
      for (int j = 0; j < 4; j++) {
        float s = 0.f, mx = -3.0e38f;
#pragma unroll
        for (int n = 0; n < 4; n++) {
          float d = acc[m][n][j];
          float e = __expf(d * TEMPW);
          s += e; mx = fmaxf(mx, d);
          colS[n] += e; colM[n] = fmaxf(colM[n], d);
        }
#pragma unroll
        for (int o = 1; o < 16; o <<= 1) {
          s  += __shfl_xor(s, o, 64);
          mx  = fmaxf(mx, __shfl_xor(mx, o, 64));
        }
        if (fr == 0) {
          int r = rbase + (m << 4) + j;
          atomicAdd(&neg_sum[r], s);
          atomicMax(&neg_max[r], enc_ord(mx));
        }
      }
    }
#pragma unroll
    for (int n = 0; n < 4; n++) {
      float s = colS[n], mx = colM[n];
      s += __shfl_xor(s, 16, 64); mx = fmaxf(mx, __shfl_xor(mx, 16, 64));
      s += __shfl_xor(s, 32, 64); mx = fmaxf(mx, __shfl_xor(mx, 32, 64));
      if (fh == 0) {
        int c = cbase + (n << 4);
        atomicAdd(&neg_sum[c], s);
        atomicMax(&neg_max[c], enc_ord(mx));
      }
    }
  } else {
    // pos tile: dump dots to scratch (compared after neg_max is final)
    float* basep = pos_dots + (size_t)(b - nn) * 16384;
#pragma unroll
    for (int m = 0; m < 4; m++)
#pragma unroll
      for (int n = 0; n < 4; n++)
        *(f32x4*)(basep + (((m << 2) + n) << 10) + (t << 2)) = acc[m][n];
  }
}

// ---- fused pos-compare + finalize (last pos block runs the finalize) -------
__global__ __launch_bounds__(256) void pos_fin_k(
    const float* __restrict__ pos_dots, const int* __restrict__ cnts,
    const int* __restrict__ pos_list, const unsigned* __restrict__ neg_max,
    const float* __restrict__ neg_sum, const int* __restrict__ ov,
    float* __restrict__ sumS, float* __restrict__ corr,
    int* __restrict__ done, float* __restrict__ out)
{
  const int np = cnts[1];
  const int p  = blockIdx.x;
  const int t  = threadIdx.x, lane = t & 63, wave = t >> 6;

  __shared__ float wsum[4];
  __shared__ int   wcnt[4];
  __shared__ int   amLast;

  if (p < np) {
    const int pr = pos_list[p];
    const int bi = pr >> 5, bj = pr & 31;
    const int wrow = (wave >> 1) << 6, wcol = (wave & 1) << 6;
    const int fr = lane & 15, fh = lane >> 4;
    const int rbase = (bi << 7) + wrow + (fh << 2);
    const int cbase = (bj << 7) + wcol + fr;
    const float cw = ((bi < 16) == (bj < 16)) ? 1.0f : 0.5f;
    const float* basep = pos_dots + (size_t)p * 16384;

    float ssum = 0.f;
    int cc = 0;
    if (bi == bj) {
#pragma unroll
      for (int m = 0; m < 4; m++)
#pragma unroll
        for (int n = 0; n < 4; n++) {
          f32x4 v = *(const f32x4*)(basep + (((m << 2) + n) << 10) + (t << 2));
          int c = cbase + (n << 4);
#pragma unroll
          for (int j = 0; j < 4; j++) {
            int r = rbase + (m << 4) + j;
            if (r != c) {
              float d = v[j];
              ssum += d;
              cc += (d > dec_ord(neg_max[r])) ? 1 : 0;
            }
          }
        }
    } else {
      float nmr[4][4], nmc[4];
#pragma unroll
      for (int m = 0; m < 4; m++)
#pragma unroll
        for (int j = 0; j < 4; j++) nmr[m][j] = dec_ord(neg_max[rbase + (m << 4) + j]);
#pragma unroll
      for (int n = 0; n < 4; n++) nmc[n] = dec_ord(neg_max[cbase + (n << 4)]);
#pragma unroll
      for (int m = 0; m < 4; m++)
#pragma unroll
        for (int n = 0; n < 4; n++) {
          f32x4 v = *(const f32x4*)(basep + (((m << 2) + n) << 10) + (t << 2));
#pragma unroll
          for (int j = 0; j < 4; j++) {
            float d = v[j];
            ssum += d;
            cc += ((d > nmr[m][j]) ? 1 : 0) + ((d > nmc[n]) ? 1 : 0);
          }
        }
      ssum *= 2.0f;   // both orientations
    }
    ssum *= cw;

#pragma unroll
    for (int o = 1; o < 64; o <<= 1) {
      ssum += __shfl_xor(ssum, o, 64);
      cc   += __shfl_xor(cc, o, 64);
    }
    if (lane == 0) { wsum[wave] = ssum; wcnt[wave] = cc; }
    __syncthreads();
    if (t == 0) {
      float S2 = 0.f; int C2 = 0;
      for (int w = 0; w < 4; w++) { S2 += wsum[w]; C2 += wcnt[w]; }
      atomicAdd(sumS, S2);
      atomicAdd(corr, (float)C2);
    }
  }

  // completion detection (block-uniform broadcast via shared)
  if (t == 0) {
    int my = -1;
    if (p < np) { __threadfence(); my = atomicAdd(done, 1); }
    amLast = (my == np - 1) ? 1 : 0;
  }
  __syncthreads();
  if (!amLast) return;
  __threadfence();

  // finalize: loss = (sum_r W_r*log(neg_sum_r) - TEMP*sumS) / total_pos
  float aa = 0.f;
  for (int r = t; r < NT; r += 256) {
    int g = r >> 8;                     // 256-row group, 0..15
    float W = ov[g & 7] ? 383.f : 255.f;
    aa += W * __logf(neg_sum[r]);
  }
#pragma unroll
  for (int o = 1; o < 64; o <<= 1) aa += __shfl_xor(aa, o, 64);
  if (lane == 0) wsum[wave] = aa;
  __syncthreads();
  if (t == 0) {
    float sw = wsum[0] + wsum[1] + wsum[2] + wsum[3];
    float S = atomicAdd(sumS, 0.f);     // coherent read past L1
    float C = atomicAdd(corr, 0.f);
    float tp = 0.f;
    for (int g = 0; g < 16; g++) tp += 256.f * (255.f + 256.f * (ov[g & 7] ? 1.f : 0.f));
    out[0] = C / tp;
    out[1] = (sw - TEMPW * S) / tp;
  }
}

// ---- launch ----------------------------------------------------------------

extern "C" void kernel_launch(void* const* d_in, const int* in_sizes, int n_in,
                              void* d_out, int out_size, void* d_ws, size_t ws_size,
                              hipStream_t stream)
{
  const float* f1 = (const float*)d_in[0];
  const float* f2 = (const float*)d_in[1];
  const int*   ov = (const int*)d_in[2];

  char* ws = (char*)d_ws;
  ushort_t* bf       = (ushort_t*)ws;                                    // 4 MB
  float*    neg_sum  = (float*)(ws + (size_t)(4 << 20));                 // 16 KB
  unsigned* neg_max  = (unsigned*)(ws + (size_t)(4 << 20) + (16 << 10)); // 16 KB
  float*    sumS     = (float*)(ws + (size_t)(4 << 20) + (32 << 10));
  float*    corr     = sumS + 1;
  int*      cnts     = (int*)(sumS + 2);                                 // 3 ints
  int*      done     = cnts + 2;                                         // alias cnts[2]
  int*      neg_list = (int*)(ws + (size_t)(4 << 20) + (36 << 10));      // <=496
  int*      pos_list = (int*)(ws + (size_t)(4 << 20) + (40 << 10));      // <=80
  float*    pos_dots = (float*)(ws + (size_t)(4 << 20) + (64 << 10));    // 5.25 MB
  float*    out      = (float*)d_out;

  hipLaunchKernelGGL(prep_k, dim3(1024), dim3(256), 0, stream,
                     f1, f2, bf, neg_sum, neg_max, sumS, corr, cnts,
                     neg_list, pos_list, ov);
  hipLaunchKernelGGL(gram_k, dim3(528), dim3(256), 0, stream,
                     bf, cnts, neg_list, pos_list, neg_sum, neg_max, pos_dots);
  hipLaunchKernelGGL(pos_fin_k, dim3(80), dim3(256), 0, stream,
                     pos_dots, cnts, pos_list, neg_max, neg_sum, ov,
                     sumS, corr, done, out);
}